// Round 7
// baseline (167.317 us; speedup 1.0000x reference)
//
#include <hip/hip_runtime.h>

#define NN 40000
#define NE 640000
#define BN_EPS 1e-5f

typedef __attribute__((ext_vector_type(8))) short bf16x8;
typedef __attribute__((ext_vector_type(4))) float f32x4;
typedef unsigned int uint;
typedef unsigned short ushort;

__device__ __forceinline__ float blo(uint u) { return __uint_as_float(u << 16); }
__device__ __forceinline__ float bhi(uint u) { return __uint_as_float(u & 0xFFFF0000u); }
__device__ __forceinline__ uint bpack(float lo, float hi) {
    uint a = __float_as_uint(lo); a = (a + 0x7FFFu + ((a >> 16) & 1u)) >> 16;        // RNE
    uint b = __float_as_uint(hi); b = (b + 0x7FFFu + ((b >> 16) & 1u)) & 0xFFFF0000u;
    return a | b;
}
__device__ __forceinline__ ushort b1pack(float v) {
    uint u = __float_as_uint(v); return (ushort)((u + 0x7FFFu + ((u >> 16) & 1u)) >> 16);
}
__device__ __forceinline__ uint4 cvt8(const float4* f4, int i) {
    float4 p = f4[i * 2], q = f4[i * 2 + 1];
    uint4 o;
    o.x = bpack(p.x, p.y); o.y = bpack(p.z, p.w);
    o.z = bpack(q.x, q.y); o.w = bpack(q.z, q.w);
    return o;
}

// ---------------- K1: bucket edges || convert x,W1,W2 -> bf16 || zero bn ----------------
// cnt must be zeroed before launch (hipMemsetAsync node). Disjoint block ranges.
__global__ __launch_bounds__(256) void k_prep(const float* __restrict__ x, const float* __restrict__ W1,
                                              const float* __restrict__ W2, const int* __restrict__ ei,
                                              int* __restrict__ cnt, float* __restrict__ bn,
                                              uint* __restrict__ xb, uint* __restrict__ w1b,
                                              uint* __restrict__ w2b, ushort* __restrict__ srcl) {
    int b = blockIdx.x, t = threadIdx.x;
    if (b < 2500) {                                   // bucket: 1 int atomic per edge
        int e = b * 256 + t;
        int s = ei[e];
        int d = ei[NE + e];
        int pos = atomicAdd(&cnt[d], 1);
        if (pos < 64) srcl[d * 64 + pos] = (ushort)s;
    } else if (b < 5000) {                            // x -> bf16 (640000 uint4-groups)
        int i = (b - 2500) * 256 + t;
        ((uint4*)xb)[i] = cvt8((const float4*)x, i);
    } else if (b < 5008) {                            // W1 -> bf16 (2048 groups)
        int i = (b - 5000) * 256 + t;
        ((uint4*)w1b)[i] = cvt8((const float4*)W1, i);
    } else if (b < 5016) {                            // W2 -> bf16
        int i = (b - 5008) * 256 + t;
        ((uint4*)w2b)[i] = cvt8((const float4*)W2, i);
    } else {                                          // zero bnsum/bnsumsq
        bn[t] = 0.f;
    }
}

// one masked chunk of 8 neighbors for one node (indices clamped to row 0, values masked)
__device__ __forceinline__ void gchunk(int sv, int deg, int i, int lane,
                                       const uint* __restrict__ xbv, float& a0, float& a1) {
#pragma unroll
    for (int j = 0; j < 8; ++j) {
        int idx = i + j;
        int s = __builtin_amdgcn_readlane(sv, idx);   // SALU broadcast
        bool ok = idx < deg;
        s = ok ? s : 0;                               // s_cselect (deg wave-uniform)
        uint v = xbv[(size_t)s * 64 + lane];
        a0 += ok ? blo(v) : 0.f;
        a1 += ok ? bhi(v) : 0.f;
    }
}

// ---------------- K2: fused gather (-> LDS) + GEMM1 MFMA + BN stats ----------------
// Block owns 64 rows. Phase 1: 4 waves x 16 nodes (processed in independent PAIRS for MLP)
// gather bf16 rows into LDS tile [64][136] ushort (row stride 68 dwords = 4 banks mod 32
// -> 2-way aliasing on ds_read_b128 A-frags, free per m136). Phase 2: mm1 from LDS,
// h1b global write, fused BN sum/sumsq block-reduce + atomics.
__global__ __launch_bounds__(256) void k_gmm1(const uint* __restrict__ xbv, const int* __restrict__ cnt,
                                              const ushort* __restrict__ srcl, const float* __restrict__ epsp,
                                              const ushort* __restrict__ w1b, const float* __restrict__ b1,
                                              ushort* __restrict__ h1b,
                                              float* __restrict__ bnsum, float* __restrict__ bnsumsq) {
    __shared__ alignas(16) char smem[17408];          // 64*136*2 B tile; aliased as stats buffers later
    uint* hu = (uint*)smem;                           // row r at hu[r*68 .. r*68+63]
    const int tid = threadIdx.x;
    const int wave = tid >> 6;
    const int lane = tid & 63;
    const float e1 = 1.f + epsp[0];
    const int nbase = blockIdx.x * 64 + wave * 16;

    // ---- phase 1: gather 16 nodes per wave, as 8 independent pairs ----
    for (int p = 0; p < 8; ++p) {
        int nA = nbase + p * 2, nB = nA + 1;
        int degA = cnt[nA]; degA = degA > 64 ? 64 : degA;
        int degB = cnt[nB]; degB = degB > 64 ? 64 : degB;
        int svA = srcl[(size_t)nA * 64 + lane];
        int svB = srcl[(size_t)nB * 64 + lane];
        uint suA = xbv[(size_t)nA * 64 + lane];
        uint suB = xbv[(size_t)nB * 64 + lane];
        float a0A = blo(suA) * e1, a1A = bhi(suA) * e1;
        float a0B = blo(suB) * e1, a1B = bhi(suB) * e1;
        int cA = (degA + 7) >> 3, cB = (degB + 7) >> 3;
        int cm = cA > cB ? cA : cB;
        for (int c = 0; c < cm; ++c) {                // A+B chunks interleaved: 16 loads in flight
            gchunk(svA, degA, c * 8, lane, xbv, a0A, a1A);
            gchunk(svB, degB, c * 8, lane, xbv, a0B, a1B);
        }
        int rA = wave * 16 + p * 2;
        hu[rA * 68 + lane]       = bpack(a0A, a1A);
        hu[(rA + 1) * 68 + lane] = bpack(a0B, a1B);
    }
    __syncthreads();

    // ---- phase 2: mm1 (MFMA bf16) from LDS ----
    // fragments: A[row=l&15][k=(l>>4)*8+j], B[k][col=l&15], C/D col=l&15,row=(l>>4)*4+i
    const int lr = lane & 15;
    const int lk = lane >> 4;
    const int r0l = wave * 16;                        // local row base
    const int r0 = blockIdx.x * 64 + r0l;             // global row base

    bf16x8 a[4];
#pragma unroll
    for (int ks = 0; ks < 4; ++ks)
        a[ks] = *reinterpret_cast<const bf16x8*>((const ushort*)smem + (r0l + lr) * 136 + ks * 32 + lk * 8);
    __syncthreads();                                  // tile free; smem becomes rs/rq

    f32x4 acc[8];
#pragma unroll
    for (int t = 0; t < 8; ++t) { acc[t][0] = 0.f; acc[t][1] = 0.f; acc[t][2] = 0.f; acc[t][3] = 0.f; }

#pragma unroll
    for (int t = 0; t < 8; ++t) {
        const ushort* wrow = &w1b[(size_t)(t * 16 + lr) * 128];
#pragma unroll
        for (int ks = 0; ks < 4; ++ks) {
            bf16x8 bfr = *reinterpret_cast<const bf16x8*>(&wrow[ks * 32 + lk * 8]);
            acc[t] = __builtin_amdgcn_mfma_f32_16x16x32_bf16(a[ks], bfr, acc[t], 0, 0, 0);
        }
    }

    float* rs = (float*)smem;                         // 256*8 f32 = 8KB
    float* rq = rs + 2048;                            // 8KB
#pragma unroll
    for (int t = 0; t < 8; ++t) {
        float bias = b1[t * 16 + lr];
        float s = 0.f, q = 0.f;
#pragma unroll
        for (int i = 0; i < 4; ++i) {
            float v = acc[t][i] + bias;
            h1b[(size_t)(r0 + lk * 4 + i) * 128 + t * 16 + lr] = b1pack(v);
            s += v; q += v * v;
        }
        rs[tid * 8 + t] = s;
        rq[tid * 8 + t] = q;
    }
    __syncthreads();
    if (tid < 128) {
        int c = tid, t = c >> 4, cr = c & 15;
        float s = 0.f, q = 0.f;
#pragma unroll
        for (int w = 0; w < 4; ++w)
#pragma unroll
            for (int g = 0; g < 4; ++g) {
                int src = w * 64 + g * 16 + cr;
                s += rs[src * 8 + t];
                q += rq[src * 8 + t];
            }
        atomicAdd(&bnsum[c], s);
        atomicAdd(&bnsumsq[c], q);
    }
}

// ---------------- K3: GEMM2 (MFMA bf16): out = relu(bn(h1)) @ W2b^T + b2, BN inline ----------------
__global__ __launch_bounds__(256) void k_mm2(const ushort* __restrict__ h1b, const ushort* __restrict__ w2b,
                                             const float* __restrict__ b2,
                                             const float* __restrict__ bnsum, const float* __restrict__ bnsumsq,
                                             const float* __restrict__ gamma, const float* __restrict__ beta,
                                             float* __restrict__ out) {
    __shared__ float ssc[128], ssh[128];
    const int tid = threadIdx.x;
    if (tid < 128) {
        float mu = bnsum[tid] * (1.0f / NN);
        float var = bnsumsq[tid] * (1.0f / NN) - mu * mu;
        float rsv = rsqrtf(var + BN_EPS);
        float g = rsv * gamma[tid];
        ssc[tid] = g;
        ssh[tid] = beta[tid] - mu * g;
    }
    __syncthreads();

    const int wave = tid >> 6;
    const int lane = tid & 63;
    const int lr = lane & 15;
    const int lk = lane >> 4;
    const int r0 = (blockIdx.x * 4 + wave) * 16;

    bf16x8 a[4];
#pragma unroll
    for (int ks = 0; ks < 4; ++ks) {
        int kbase = ks * 32 + lk * 8;
        bf16x8 raw = *reinterpret_cast<const bf16x8*>(&h1b[(size_t)(r0 + lr) * 128 + kbase]);
        bf16x8 o;
#pragma unroll
        for (int j = 0; j < 8; ++j) {
            float v = __uint_as_float(((uint)(ushort)raw[j]) << 16);
            v = fmaxf(0.f, fmaf(v, ssc[kbase + j], ssh[kbase + j]));
            o[j] = (short)b1pack(v);
        }
        a[ks] = o;
    }

    f32x4 acc[8];
#pragma unroll
    for (int t = 0; t < 8; ++t) { acc[t][0] = 0.f; acc[t][1] = 0.f; acc[t][2] = 0.f; acc[t][3] = 0.f; }

#pragma unroll
    for (int t = 0; t < 8; ++t) {
        const ushort* wrow = &w2b[(size_t)(t * 16 + lr) * 128];
#pragma unroll
        for (int ks = 0; ks < 4; ++ks) {
            bf16x8 bfr = *reinterpret_cast<const bf16x8*>(&wrow[ks * 32 + lk * 8]);
            acc[t] = __builtin_amdgcn_mfma_f32_16x16x32_bf16(a[ks], bfr, acc[t], 0, 0, 0);
        }
    }
#pragma unroll
    for (int t = 0; t < 8; ++t) {
        float bias = b2[t * 16 + lr];
#pragma unroll
        for (int i = 0; i < 4; ++i)
            out[(size_t)(r0 + lk * 4 + i) * 128 + t * 16 + lr] = acc[t][i] + bias;
    }
}

extern "C" void kernel_launch(void* const* d_in, const int* in_sizes, int n_in,
                              void* d_out, int out_size, void* d_ws, size_t ws_size,
                              hipStream_t stream) {
    const float* x     = (const float*)d_in[0];
    const int*   ei    = (const int*)d_in[1];
    const float* W1    = (const float*)d_in[2];
    const float* b1    = (const float*)d_in[3];
    const float* gamma = (const float*)d_in[4];
    const float* beta  = (const float*)d_in[5];
    const float* W2    = (const float*)d_in[6];
    const float* b2    = (const float*)d_in[7];
    const float* eps   = (const float*)d_in[8];

    char* ws = (char*)d_ws;
    // ws layout (256B-aligned): cnt i32[40000] | srcl u16[40000*64] | xb bf16[40000*128] |
    //   h1b bf16[40000*128] | w1b bf16[128*128] | w2b bf16[128*128] | bn f32[256]
    int*    cnt  = (int*)(ws + 0);
    ushort* srcl = (ushort*)(ws + 160000);
    uint*   xb   = (uint*)(ws + 5280000);
    ushort* h1b  = (ushort*)(ws + 15520000);
    uint*   w1b  = (uint*)(ws + 25760000);
    uint*   w2b  = (uint*)(ws + 25792768);
    float*  bn   = (float*)(ws + 25825536);
    float* bnsum   = bn;
    float* bnsumsq = bn + 128;

    hipMemsetAsync(cnt, 0, 160000, stream);
    k_prep<<<5017, 256, 0, stream>>>(x, W1, W2, ei, cnt, bn, xb, w1b, w2b, srcl);
    k_gmm1<<<625, 256, 0, stream>>>(xb, cnt, srcl, eps, (const ushort*)w1b, b1, h1b, bnsum, bnsumsq);
    k_mm2<<<625, 256, 0, stream>>>(h1b, (const ushort*)w2b, b2, bnsum, bnsumsq, gamma, beta, (float*)d_out);
}

// Round 8
// 111.546 us; speedup vs baseline: 1.5000x; 1.5000x over previous
//
#include <hip/hip_runtime.h>

#define NN 40000
#define NE 640000
#define BN_EPS 1e-5f

typedef __attribute__((ext_vector_type(8))) short bf16x8;
typedef __attribute__((ext_vector_type(4))) float f32x4;
typedef unsigned int uint;
typedef unsigned short ushort;

__device__ __forceinline__ float blo(uint u) { return __uint_as_float(u << 16); }
__device__ __forceinline__ float bhi(uint u) { return __uint_as_float(u & 0xFFFF0000u); }
__device__ __forceinline__ uint bpack(float lo, float hi) {
    uint a = __float_as_uint(lo); a = (a + 0x7FFFu + ((a >> 16) & 1u)) >> 16;        // RNE
    uint b = __float_as_uint(hi); b = (b + 0x7FFFu + ((b >> 16) & 1u)) & 0xFFFF0000u;
    return a | b;
}
__device__ __forceinline__ ushort b1pack(float v) {
    uint u = __float_as_uint(v); return (ushort)((u + 0x7FFFu + ((u >> 16) & 1u)) >> 16);
}
__device__ __forceinline__ uint4 cvt8(const float4* f4, int i) {
    float4 p = f4[i * 2], q = f4[i * 2 + 1];
    uint4 o;
    o.x = bpack(p.x, p.y); o.y = bpack(p.z, p.w);
    o.z = bpack(q.x, q.y); o.w = bpack(q.z, q.w);
    return o;
}

// ---------------- K1: bucket edges || convert x,W1,W2 -> bf16 || zero bn ----------------
// cnt pre-zeroed by hipMemsetAsync. Disjoint block ranges -> atomic-heavy bucket phase
// co-runs with BW-heavy converts instead of serializing (R6 had them as 2 serial kernels).
__global__ __launch_bounds__(256) void k_prep(const float* __restrict__ x, const float* __restrict__ W1,
                                              const float* __restrict__ W2, const int* __restrict__ ei,
                                              int* __restrict__ cnt, float* __restrict__ bn,
                                              uint* __restrict__ xb, uint* __restrict__ w1b,
                                              uint* __restrict__ w2b, ushort* __restrict__ srcl) {
    int b = blockIdx.x, t = threadIdx.x;
    if (b < 2500) {                                   // bucket: 1 int atomic per edge
        int e = b * 256 + t;
        int s = ei[e];
        int d = ei[NE + e];
        int pos = atomicAdd(&cnt[d], 1);
        if (pos < 64) srcl[d * 64 + pos] = (ushort)s;
    } else if (b < 5000) {                            // x -> bf16 (640000 uint4-groups)
        int i = (b - 2500) * 256 + t;
        ((uint4*)xb)[i] = cvt8((const float4*)x, i);
    } else if (b < 5008) {                            // W1 -> bf16 (2048 groups)
        int i = (b - 5000) * 256 + t;
        ((uint4*)w1b)[i] = cvt8((const float4*)W1, i);
    } else if (b < 5016) {                            // W2 -> bf16
        int i = (b - 5008) * 256 + t;
        ((uint4*)w2b)[i] = cvt8((const float4*)W2, i);
    } else {                                          // zero bnsum/bnsumsq
        bn[t] = 0.f;
    }
}

// ---------------- K2: wave-per-node bf16 gather (R6 known-good), 4 rows per load ----------------
__global__ __launch_bounds__(256) void k_gather(const uint4* __restrict__ xq, const int* __restrict__ cnt,
                                                const ushort* __restrict__ srcl, const float* __restrict__ epsp,
                                                uint4* __restrict__ hbq) {
    int wid = blockIdx.x * 4 + (threadIdx.x >> 6);    // one wave per node; grid*4 == NN
    int lane = threadIdx.x & 63;
    int grp = lane >> 4;                              // neighbor slot 0..3
    int cidx = lane & 15;                             // channel quad (8 ch)
    int deg = cnt[wid]; deg = deg > 64 ? 64 : deg;
    int sv = srcl[wid * 64 + lane];                   // neighbor ids, one per lane

    float acc[8];
#pragma unroll
    for (int j = 0; j < 8; ++j) acc[j] = 0.f;

    int chunks = (deg + 7) >> 3;
    for (int c = 0; c < chunks; ++c) {
        int i = c * 8;
        int n0 = i + grp, n1 = i + 4 + grp;
        int s0 = __shfl(sv, n0);
        int s1 = __shfl(sv, n1);
        float m0 = n0 < deg ? 1.f : 0.f;
        float m1 = n1 < deg ? 1.f : 0.f;
        s0 = n0 < deg ? s0 : 0;
        s1 = n1 < deg ? s1 : 0;
        uint4 v0 = xq[(size_t)s0 * 16 + cidx];        // 4 rows per instruction
        uint4 v1 = xq[(size_t)s1 * 16 + cidx];
        acc[0] = fmaf(blo(v0.x), m0, acc[0]); acc[1] = fmaf(bhi(v0.x), m0, acc[1]);
        acc[2] = fmaf(blo(v0.y), m0, acc[2]); acc[3] = fmaf(bhi(v0.y), m0, acc[3]);
        acc[4] = fmaf(blo(v0.z), m0, acc[4]); acc[5] = fmaf(bhi(v0.z), m0, acc[5]);
        acc[6] = fmaf(blo(v0.w), m0, acc[6]); acc[7] = fmaf(bhi(v0.w), m0, acc[7]);
        acc[0] = fmaf(blo(v1.x), m1, acc[0]); acc[1] = fmaf(bhi(v1.x), m1, acc[1]);
        acc[2] = fmaf(blo(v1.y), m1, acc[2]); acc[3] = fmaf(bhi(v1.y), m1, acc[3]);
        acc[4] = fmaf(blo(v1.z), m1, acc[4]); acc[5] = fmaf(bhi(v1.z), m1, acc[5]);
        acc[6] = fmaf(blo(v1.w), m1, acc[6]); acc[7] = fmaf(bhi(v1.w), m1, acc[7]);
    }
#pragma unroll
    for (int j = 0; j < 8; ++j) {
        acc[j] += __shfl_xor(acc[j], 16);
        acc[j] += __shfl_xor(acc[j], 32);
    }
    if (grp == 0) {                                   // lanes 0-15: add (1+eps)*self, pack, store
        float e1 = 1.f + epsp[0];
        uint4 s = xq[(size_t)wid * 16 + cidx];
        uint4 o;
        o.x = bpack(fmaf(blo(s.x), e1, acc[0]), fmaf(bhi(s.x), e1, acc[1]));
        o.y = bpack(fmaf(blo(s.y), e1, acc[2]), fmaf(bhi(s.y), e1, acc[3]));
        o.z = bpack(fmaf(blo(s.z), e1, acc[4]), fmaf(bhi(s.z), e1, acc[5]));
        o.w = bpack(fmaf(blo(s.w), e1, acc[6]), fmaf(bhi(s.w), e1, acc[7]));
        hbq[(size_t)wid * 16 + cidx] = o;
    }
}

// ---------------- K3: GEMM1 (MFMA bf16): h1b = bf16(hb @ W1b^T + b1), fused BN stats ----------------
// fragments: A[row=l&15][k=(l>>4)*8+j], B[k][col=l&15], C/D col=l&15,row=(l>>4)*4+i
__global__ __launch_bounds__(256) void k_mm1(const ushort* __restrict__ hb, const ushort* __restrict__ w1b,
                                             const float* __restrict__ b1, ushort* __restrict__ h1b,
                                             float* __restrict__ bnsum, float* __restrict__ bnsumsq) {
    __shared__ float rs[256 * 8];
    __shared__ float rq[256 * 8];
    const int tid = threadIdx.x;
    const int wave = tid >> 6;
    const int lane = tid & 63;
    const int lr = lane & 15;
    const int lk = lane >> 4;
    const int r0 = (blockIdx.x * 4 + wave) * 16;     // 625 blocks * 4 waves * 16 rows = 40000

    bf16x8 a[4];
#pragma unroll
    for (int ks = 0; ks < 4; ++ks)
        a[ks] = *reinterpret_cast<const bf16x8*>(&hb[(size_t)(r0 + lr) * 128 + ks * 32 + lk * 8]);

    f32x4 acc[8];
#pragma unroll
    for (int t = 0; t < 8; ++t) { acc[t][0] = 0.f; acc[t][1] = 0.f; acc[t][2] = 0.f; acc[t][3] = 0.f; }

#pragma unroll
    for (int t = 0; t < 8; ++t) {
        const ushort* wrow = &w1b[(size_t)(t * 16 + lr) * 128];
#pragma unroll
        for (int ks = 0; ks < 4; ++ks) {
            bf16x8 bfr = *reinterpret_cast<const bf16x8*>(&wrow[ks * 32 + lk * 8]);
            acc[t] = __builtin_amdgcn_mfma_f32_16x16x32_bf16(a[ks], bfr, acc[t], 0, 0, 0);
        }
    }
#pragma unroll
    for (int t = 0; t < 8; ++t) {
        float bias = b1[t * 16 + lr];
        float s = 0.f, q = 0.f;
#pragma unroll
        for (int i = 0; i < 4; ++i) {
            float v = acc[t][i] + bias;
            h1b[(size_t)(r0 + lk * 4 + i) * 128 + t * 16 + lr] = b1pack(v);
            s += v; q += v * v;
        }
        rs[tid * 8 + t] = s;
        rq[tid * 8 + t] = q;
    }
    __syncthreads();
    if (tid < 128) {
        int c = tid, t = c >> 4, cr = c & 15;
        float s = 0.f, q = 0.f;
#pragma unroll
        for (int w = 0; w < 4; ++w)
#pragma unroll
            for (int g = 0; g < 4; ++g) {
                int src = w * 64 + g * 16 + cr;
                s += rs[src * 8 + t];
                q += rq[src * 8 + t];
            }
        atomicAdd(&bnsum[c], s);
        atomicAdd(&bnsumsq[c], q);
    }
}

// ---------------- K4: GEMM2 (MFMA bf16): out = relu(bn(h1)) @ W2b^T + b2, BN inline ----------------
__global__ __launch_bounds__(256) void k_mm2(const ushort* __restrict__ h1b, const ushort* __restrict__ w2b,
                                             const float* __restrict__ b2,
                                             const float* __restrict__ bnsum, const float* __restrict__ bnsumsq,
                                             const float* __restrict__ gamma, const float* __restrict__ beta,
                                             float* __restrict__ out) {
    __shared__ float ssc[128], ssh[128];
    const int tid = threadIdx.x;
    if (tid < 128) {
        float mu = bnsum[tid] * (1.0f / NN);
        float var = bnsumsq[tid] * (1.0f / NN) - mu * mu;
        float rsv = rsqrtf(var + BN_EPS);
        float g = rsv * gamma[tid];
        ssc[tid] = g;
        ssh[tid] = beta[tid] - mu * g;
    }
    __syncthreads();

    const int wave = tid >> 6;
    const int lane = tid & 63;
    const int lr = lane & 15;
    const int lk = lane >> 4;
    const int r0 = (blockIdx.x * 4 + wave) * 16;

    bf16x8 a[4];
#pragma unroll
    for (int ks = 0; ks < 4; ++ks) {
        int kbase = ks * 32 + lk * 8;
        bf16x8 raw = *reinterpret_cast<const bf16x8*>(&h1b[(size_t)(r0 + lr) * 128 + kbase]);
        bf16x8 o;
#pragma unroll
        for (int j = 0; j < 8; ++j) {
            float v = __uint_as_float(((uint)(ushort)raw[j]) << 16);
            v = fmaxf(0.f, fmaf(v, ssc[kbase + j], ssh[kbase + j]));
            o[j] = (short)b1pack(v);
        }
        a[ks] = o;
    }

    f32x4 acc[8];
#pragma unroll
    for (int t = 0; t < 8; ++t) { acc[t][0] = 0.f; acc[t][1] = 0.f; acc[t][2] = 0.f; acc[t][3] = 0.f; }

#pragma unroll
    for (int t = 0; t < 8; ++t) {
        const ushort* wrow = &w2b[(size_t)(t * 16 + lr) * 128];
#pragma unroll
        for (int ks = 0; ks < 4; ++ks) {
            bf16x8 bfr = *reinterpret_cast<const bf16x8*>(&wrow[ks * 32 + lk * 8]);
            acc[t] = __builtin_amdgcn_mfma_f32_16x16x32_bf16(a[ks], bfr, acc[t], 0, 0, 0);
        }
    }
#pragma unroll
    for (int t = 0; t < 8; ++t) {
        float bias = b2[t * 16 + lr];
#pragma unroll
        for (int i = 0; i < 4; ++i)
            out[(size_t)(r0 + lk * 4 + i) * 128 + t * 16 + lr] = acc[t][i] + bias;
    }
}

extern "C" void kernel_launch(void* const* d_in, const int* in_sizes, int n_in,
                              void* d_out, int out_size, void* d_ws, size_t ws_size,
                              hipStream_t stream) {
    const float* x     = (const float*)d_in[0];
    const int*   ei    = (const int*)d_in[1];
    const float* W1    = (const float*)d_in[2];
    const float* b1    = (const float*)d_in[3];
    const float* gamma = (const float*)d_in[4];
    const float* beta  = (const float*)d_in[5];
    const float* W2    = (const float*)d_in[6];
    const float* b2    = (const float*)d_in[7];
    const float* eps   = (const float*)d_in[8];

    char* ws = (char*)d_ws;
    // ws layout (256B-aligned): cnt i32[40000] | srcl u16[40000*64] | xb bf16[40000*128] |
    //   hb bf16[40000*128] | h1b bf16[40000*128] | w1b bf16[128*128] | w2b bf16[128*128] | bn f32[256]
    int*    cnt  = (int*)(ws + 0);
    ushort* srcl = (ushort*)(ws + 160000);
    uint*   xb   = (uint*)(ws + 5280000);
    uint*   hb   = (uint*)(ws + 15520000);
    ushort* h1b  = (ushort*)(ws + 25760000);
    uint*   w1b  = (uint*)(ws + 36000000);
    uint*   w2b  = (uint*)(ws + 36032768);
    float*  bn   = (float*)(ws + 36065536);
    float* bnsum   = bn;
    float* bnsumsq = bn + 128;

    hipMemsetAsync(cnt, 0, 160000, stream);
    k_prep<<<5017, 256, 0, stream>>>(x, W1, W2, ei, cnt, bn, xb, w1b, w2b, srcl);
    k_gather<<<10000, 256, 0, stream>>>((const uint4*)xb, cnt, srcl, eps, (uint4*)hb);
    k_mm1<<<625, 256, 0, stream>>>((const ushort*)hb, (const ushort*)w1b, b1, h1b, bnsum, bnsumsq);
    k_mm2<<<625, 256, 0, stream>>>(h1b, (const ushort*)w2b, b2, bnsum, bnsumsq, gamma, beta, (float*)d_out);
}